// Round 4
// baseline (239.249 us; speedup 1.0000x reference)
//
#include <hip/hip_runtime.h>
#include <hip/hip_bf16.h>
#include <cstdint>

// ---------- types ----------
typedef __attribute__((ext_vector_type(4))) float f32x4;
typedef __attribute__((ext_vector_type(16))) float f32x16;
typedef __attribute__((ext_vector_type(8))) __bf16 bf16x8;
typedef __attribute__((ext_vector_type(4))) unsigned u32x4;

#define SCALE_Q 0.08838834764831845f  /* 1/sqrt(128) */

__device__ __forceinline__ short bf16b(float f) {
  unsigned u = __builtin_bit_cast(unsigned, f);
  unsigned r = (u + 0x7fffu + ((u >> 16) & 1u)) >> 16;
  return (short)r;
}

__device__ __forceinline__ unsigned packbf(float lo, float hi) {
  return (unsigned)(unsigned short)bf16b(lo) |
         ((unsigned)(unsigned short)bf16b(hi) << 16);
}

__device__ __forceinline__ f32x4 mfma16(bf16x8 a, bf16x8 b, f32x4 c) {
  return __builtin_amdgcn_mfma_f32_16x16x32_bf16(a, b, c, 0, 0, 0);
}
__device__ __forceinline__ f32x16 mfma32(bf16x8 a, bf16x8 b, f32x16 c) {
  return __builtin_amdgcn_mfma_f32_32x32x16_bf16(a, b, c, 0, 0, 0);
}

__device__ __forceinline__ void async16(void* lds, const void* g) {
  __builtin_amdgcn_global_load_lds(
      (const __attribute__((address_space(1))) unsigned int*)g,
      (__attribute__((address_space(3))) unsigned int*)lds, 16, 0, 0);
}

// ---------- kernel 1: fp32 -> bf16 for queries/keys/values ----------
__global__ void cvt_x(const float* __restrict__ q, const float* __restrict__ k,
                      const float* __restrict__ v, short* __restrict__ out) {
  const float* src = (blockIdx.y == 0) ? q : (blockIdx.y == 1 ? k : v);
  short* dst = out + (size_t)blockIdx.y * 8388608;
  size_t i = (size_t)blockIdx.x * 256 + threadIdx.x;
  float4 f = reinterpret_cast<const float4*>(src)[i];
  short4 o;
  o.x = bf16b(f.x); o.y = bf16b(f.y); o.z = bf16b(f.z); o.w = bf16b(f.w);
  reinterpret_cast<short4*>(dst)[i] = o;
}

// ---------- kernel 2: transpose + convert weights -> WT[z][N][K] bf16 ----------
__global__ void cvt_w(const float* __restrict__ Wq, const float* __restrict__ Wk,
                      const float* __restrict__ Wv, const float* __restrict__ Wo,
                      short* __restrict__ out) {
  int z = blockIdx.z;
  const float* W = (z == 0) ? Wq : (z == 1) ? Wk : (z == 2) ? Wv : Wo;
  float scale = (z == 0) ? SCALE_Q : 1.0f;
  __shared__ float t[64][65];
  int n0 = blockIdx.x * 64, k0 = blockIdx.y * 64;
  int c = threadIdx.x & 63, r0 = threadIdx.x >> 6;
#pragma unroll
  for (int rr = 0; rr < 16; ++rr) {
    int r = rr * 4 + r0;
    t[r][c] = W[(size_t)(k0 + r) * 1024 + n0 + c];
  }
  __syncthreads();
  short* dst = out + (size_t)z * 1048576;
#pragma unroll
  for (int rr = 0; rr < 16; ++rr) {
    int r = rr * 4 + r0;
    dst[(size_t)(n0 + r) * 1024 + k0 + c] = bf16b(t[c][r] * scale);
  }
}

// ---------- kernel 3: 256x256 8-phase GEMM (QKV proj z=0..2, out proj z=3) ----------
// Race-free stage schedule: each LDS region is staged >=1 barrier-pair AFTER
// its last ds_read. ph1->ABeta(t+1), ph2->BBeta(t+1) (other buffer, last read
// t-1 ph4); ph3->AAlpha(t+2), ph4->BAlpha(t+2) (current buffer, last read
// ph2/ph3 of this tile). vmcnt(4) once per tile at ph4 (never 0 mid-loop).
#define PHASE(APTR, BPTR, MH, NH, STAGE_STMT, VMCNT_STMT)                      \
  {                                                                            \
    bf16x8 af[4][2], bfr[2][2];                                                \
    _Pragma("unroll") for (int mt = 0; mt < 4; ++mt)                           \
        _Pragma("unroll") for (int kk = 0; kk < 2; ++kk) {                     \
      int r = wr * 128 + MH * 64 + mt * 16 + l15;                              \
      af[mt][kk] = *(const bf16x8*)((const char*)(APTR) + r * 128 +            \
                                    ((lg * 16 + kk * 64) ^ ((r & 7) << 4)));   \
    }                                                                          \
    _Pragma("unroll") for (int nt = 0; nt < 2; ++nt)                           \
        _Pragma("unroll") for (int kk = 0; kk < 2; ++kk) {                     \
      int r = wc * 64 + NH * 32 + nt * 16 + l15;                               \
      bfr[nt][kk] = *(const bf16x8*)((const char*)(BPTR) + r * 128 +           \
                                     ((lg * 16 + kk * 64) ^ ((r & 7) << 4)));  \
    }                                                                          \
    STAGE_STMT;                                                                \
    VMCNT_STMT;                                                                \
    __builtin_amdgcn_s_barrier();                                              \
    __builtin_amdgcn_s_setprio(1);                                             \
    _Pragma("unroll") for (int kk = 0; kk < 2; ++kk)                           \
        _Pragma("unroll") for (int mt = 0; mt < 4; ++mt)                       \
            _Pragma("unroll") for (int nt = 0; nt < 2; ++nt)                   \
                acc[MH * 4 + mt][NH * 2 + nt] = mfma16(                        \
                    af[mt][kk], bfr[nt][kk], acc[MH * 4 + mt][NH * 2 + nt]);   \
    __builtin_amdgcn_s_setprio(0);                                             \
    __builtin_amdgcn_s_barrier();                                              \
  }

__global__ __launch_bounds__(512, 2) void gemm256(
    const short* __restrict__ Ab, const short* __restrict__ WT,
    const float* __restrict__ bq, const float* __restrict__ bk,
    const float* __restrict__ bv, const float* __restrict__ bo,
    short* __restrict__ Qg, short* __restrict__ Kg, short* __restrict__ Vtg,
    float* __restrict__ Out, int zbase, int nwg) {
  __shared__ short LDS[65536];  // 128 KiB: A dbuf [2][256][64] + B dbuf
  short* LA = LDS;
  short* LB = LDS + 32768;

  int id = blockIdx.x;
  int cpx = nwg >> 3;
  int swz = (id & 7) * cpx + (id >> 3);  // XCD-contiguous chunks (nwg%8==0)
  int z = zbase + (swz >> 7);
  int rem = swz & 127;
  int m0 = (rem >> 2) * 256, n0 = (rem & 3) * 256;

  const short* Ag = (zbase == 0) ? Ab + (size_t)z * 8388608 : Ab;
  const short* Bg = WT + (size_t)z * 1048576;

  int tid = threadIdx.x;
  int lane = tid & 63, wave = tid >> 6;
  int wr = wave >> 2, wc = wave & 3, l15 = lane & 15, lg = lane >> 4;

  // ---- staging (linear LDS dest, inverse-swizzled global source) ----
  auto stageA = [&](short* buf, int k0, int h) {
#pragma unroll
    for (int ld = 0; ld < 2; ++ld) {
      int row = (2 * ld + h) * 64 + (tid >> 3);
      int gc = (tid & 7) ^ (row & 7);
      async16((char*)buf + row * 128 + (tid & 7) * 16,
              (const char*)Ag + (size_t)(m0 + row) * 2048 + k0 * 2 + gc * 16);
    }
  };
  auto stageB = [&](short* buf, int k0, int h) {
#pragma unroll
    for (int ld = 0; ld < 2; ++ld) {
      int idx = tid >> 3;
      int n = (h + 2 * (idx >> 5) + 4 * ld) * 32 + (idx & 31);
      int gc = (tid & 7) ^ (n & 7);
      async16((char*)buf + n * 128 + (tid & 7) * 16,
              (const char*)Bg + (size_t)(n0 + n) * 2048 + k0 * 2 + gc * 16);
    }
  };

  f32x4 acc[8][4];
#pragma unroll
  for (int i = 0; i < 8; ++i)
#pragma unroll
    for (int j = 0; j < 4; ++j) acc[i][j] = f32x4{0.f, 0.f, 0.f, 0.f};

  // ---- prologue: tile0 {Aa,Ba,Ab,Bb} + tile1 {Aa,Ba}; vmcnt(4) keeps
  // tile1's pair in flight, guarantees tile0 fully resident ----
  stageA(LA, 0, 0); stageB(LB, 0, 0); stageA(LA, 0, 1); stageB(LB, 0, 1);
  stageA(LA + 16384, 64, 0); stageB(LB + 16384, 64, 0);
  asm volatile("s_waitcnt vmcnt(4)" ::: "memory");
  __builtin_amdgcn_s_barrier();

  // ---- main loop: 16 K-tiles, 4 phases each ----
  for (int t = 0; t < 16; ++t) {
    short* Ap = LA + (t & 1) * 16384;
    short* Bp = LB + (t & 1) * 16384;
    short* Aq = LA + ((t & 1) ^ 1) * 16384;
    short* Bq = LB + ((t & 1) ^ 1) * 16384;
    // ph1 reads Aa,Ba -> stage ABeta(t+1) into other buffer (last read t-1 ph4)
    PHASE(Ap, Bp, 0, 0, { if (t + 1 < 16) stageA(Aq, t * 64 + 64, 1); }, {});
    // ph2 reads Aa,Bb -> stage BBeta(t+1) into other buffer
    PHASE(Ap, Bp, 0, 1, { if (t + 1 < 16) stageB(Bq, t * 64 + 64, 1); }, {});
    // ph3 reads Ab,Ba -> stage AAlpha(t+2) into current buffer (Aa last read ph2)
    PHASE(Ap, Bp, 1, 0, { if (t + 2 < 16) stageA(Ap, t * 64 + 128, 0); }, {});
    // ph4 reads Ab,Bb -> stage BAlpha(t+2) (Ba last read ph3); counted vmcnt
    PHASE(Ap, Bp, 1, 1, { if (t + 2 < 16) stageB(Bp, t * 64 + 128, 0); },
          {
            if (t <= 13) asm volatile("s_waitcnt vmcnt(4)" ::: "memory");
            else if (t == 14) asm volatile("s_waitcnt vmcnt(0)" ::: "memory");
          });
  }

  // ---- epilogue ----
  if (z == 2) {
    // Vt via LDS transpose: LDS[col n 256][m 128] per wr-half, coalesced stores
    unsigned* L32 = (unsigned*)LDS;
#pragma unroll
    for (int pass = 0; pass < 2; ++pass) {
      if (wr == pass) {
#pragma unroll
        for (int nt4 = 0; nt4 < 4; ++nt4) {
          int ncol = wc * 64 + nt4 * 16 + l15;
          float bb = bv[n0 + ncol];
#pragma unroll
          for (int mt8 = 0; mt8 < 8; ++mt8) {
            unsigned lo = packbf(acc[mt8][nt4][0] + bb, acc[mt8][nt4][1] + bb);
            unsigned hi = packbf(acc[mt8][nt4][2] + bb, acc[mt8][nt4][3] + bb);
            int base = ncol * 68 + mt8 * 8 + lg * 2;
            L32[base] = lo;
            L32[base + 1] = hi;
          }
        }
      }
      asm volatile("s_waitcnt lgkmcnt(0)" ::: "memory");
      __builtin_amdgcn_s_barrier();
#pragma unroll
      for (int i = 0; i < 8; ++i) {
        int idx = i * 512 + tid;
        int col = idx >> 4, ch = idx & 15;
        u32x4 val = *(u32x4*)&L32[col * 68 + ch * 4];
        int nf = n0 + col, e_ = nf & 127, h_ = nf >> 7;
        size_t bh = (size_t)(m0 >> 11) * 8 + h_;
        int sb = ((m0 & 2047) + pass * 128 + ch * 8) ^ (((e_ >> 1) & 7) << 3);
        *(u32x4*)&Vtg[(bh * 128 + e_) * 2048 + sb] = val;
      }
      asm volatile("s_waitcnt lgkmcnt(0)" ::: "memory");
      __builtin_amdgcn_s_barrier();
    }
  } else {
    const float* bias = (z == 0) ? bq : (z == 1) ? bk : bo;
    float bsc = (z == 0) ? SCALE_Q : 1.0f;
#pragma unroll
    for (int nt4 = 0; nt4 < 4; ++nt4) {
      int n = n0 + wc * 64 + nt4 * 16 + l15;
      float bb = bias[n] * bsc;
#pragma unroll
      for (int mt8 = 0; mt8 < 8; ++mt8)
#pragma unroll
        for (int j = 0; j < 4; ++j) {
          int m = m0 + wr * 128 + mt8 * 16 + lg * 4 + j;
          float c = acc[mt8][nt4][j] + bb;
          if (z == 3) {
            Out[(size_t)m * 1024 + n] = c;
          } else {
            int s_ = m & 2047, b_ = m >> 11, h_ = n >> 7, e_ = n & 127;
            size_t bh = (size_t)b_ * 8 + h_;
            if (z == 0) Qg[(bh * 2048 + s_) * 128 + e_] = bf16b(c);
            else Kg[(bh * 2048 + s_) * 128 + (e_ ^ ((s_ & 15) << 3))] = bf16b(c);
          }
        }
    }
  }
}

// ---------- kernel 4: flash attention, 32x32 swapped-QK^T, in-register P ----------
__global__ __launch_bounds__(256, 2) void attn(const short* __restrict__ Qg,
                                               const short* __restrict__ Kg,
                                               const short* __restrict__ Vtg,
                                               short* __restrict__ Ctx) {
  __shared__ short Ks[2][8192];  // [64 s][128 e], e ^ ((s&15)<<3)
  __shared__ short Vs[2][8192];  // [64 r][(e&1)*64 + (s ^ ((r&7)<<3))], r=e>>1
  int tid = threadIdx.x;
  int lane = tid & 63, wave = tid >> 6;
  int l31 = lane & 31, h = lane >> 5;
  int bh = blockIdx.y, qb = blockIdx.x;
  int qbase = qb * 128 + wave * 32;
  const short* Qp = Qg + (size_t)bh * 2048 * 128;
  const char* Kbase = (const char*)(Kg + (size_t)bh * 2048 * 128);
  const char* Vbase = (const char*)(Vtg + (size_t)bh * 128 * 2048);

  auto stage = [&](int t, int buf) {
    int s0 = t * 64;
    char* kd = (char*)&Ks[buf][0];
    char* vd = (char*)&Vs[buf][0];
#pragma unroll
    for (int i = 0; i < 4; ++i)
      async16(kd + i * 4096 + tid * 16,
              Kbase + (size_t)s0 * 256 + i * 4096 + tid * 16);
#pragma unroll
    for (int i = 0; i < 4; ++i) {
      int e = i * 32 + 2 * (tid >> 4) + ((tid >> 3) & 1);
      async16(vd + i * 4096 + tid * 16,
              Vbase + (size_t)e * 4096 + s0 * 2 + (tid & 7) * 16);
    }
  };

  stage(0, 0);

  bf16x8 qa[8];
  const short* qrow = Qp + (size_t)(qbase + l31) * 128 + h * 8;
#pragma unroll
  for (int ksl = 0; ksl < 8; ++ksl) qa[ksl] = *(const bf16x8*)(qrow + ksl * 16);

  f32x16 acc[4];
#pragma unroll
  for (int i = 0; i < 4; ++i)
#pragma unroll
    for (int r = 0; r < 16; ++r) acc[i][r] = 0.f;
  float mrun = -1e30f, lrun = 0.f;

  int swK = (l31 & 15) << 3;
  int swV = ((l31 >> 1) & 7) << 3;

  for (int t = 0; t < 32; ++t) {
    int cur = t & 1;
    if (t < 31) {
      stage(t + 1, cur ^ 1);
      asm volatile("s_waitcnt vmcnt(8)" ::: "memory");
    } else {
      asm volatile("s_waitcnt vmcnt(0)" ::: "memory");
    }
    __builtin_amdgcn_s_barrier();

    const short* Kc = Ks[cur];
    const short* Vc = Vs[cur];

    f32x16 st0, st1;
#pragma unroll
    for (int r = 0; r < 16; ++r) { st0[r] = 0.f; st1[r] = 0.f; }
    __builtin_amdgcn_s_setprio(1);
#pragma unroll
    for (int ksl = 0; ksl < 8; ++ksl) {
      int col = (ksl * 16 + h * 8) ^ swK;
      bf16x8 ka0 = *(const bf16x8*)&Kc[l31 * 128 + col];
      bf16x8 ka1 = *(const bf16x8*)&Kc[(32 + l31) * 128 + col];
      st0 = mfma32(ka0, qa[ksl], st0);
      st1 = mfma32(ka1, qa[ksl], st1);
    }
    __builtin_amdgcn_s_setprio(0);

    float mx = st0[0];
#pragma unroll
    for (int r = 1; r < 16; ++r) mx = fmaxf(mx, st0[r]);
#pragma unroll
    for (int r = 0; r < 16; ++r) mx = fmaxf(mx, st1[r]);
    mx = fmaxf(mx, __shfl_xor(mx, 32));
    int skip = __all(mx - mrun <= 5.0f);
    float mn = mrun, sf = 1.f;
    if (!skip) {
      mn = fmaxf(mrun, mx);
      sf = __expf(mrun - mn);
      mrun = mn;
    }
    float rs = 0.f;
#pragma unroll
    for (int r = 0; r < 16; ++r) { float p = __expf(st0[r] - mn); st0[r] = p; rs += p; }
#pragma unroll
    for (int r = 0; r < 16; ++r) { float p = __expf(st1[r] - mn); st1[r] = p; rs += p; }
    rs += __shfl_xor(rs, 32);
    if (!skip) {
      lrun = lrun * sf + rs;
#pragma unroll
      for (int reg = 0; reg < 16; ++reg) {
        float s4 = __shfl(sf, (reg & 3) + 8 * (reg >> 2) + 4 * h);
#pragma unroll
        for (int nte = 0; nte < 4; ++nte) acc[nte][reg] *= s4;
      }
    } else {
      lrun += rs;
    }

    unsigned w0[8], w1[8];
#pragma unroll
    for (int m = 0; m < 8; ++m) {
      w0[m] = packbf(st0[2 * m], st0[2 * m + 1]);
      w1[m] = packbf(st1[2 * m], st1[2 * m + 1]);
    }
    bf16x8 pa[4];
#pragma unroll
    for (int ks = 0; ks < 4; ++ks) {
      const unsigned* w = (ks & 2) ? w1 : w0;
      int mb = (ks & 1) * 4;
      unsigned a0 = w[mb], b0 = w[mb + 2];
      unsigned a1 = w[mb + 1], b1 = w[mb + 3];
      asm volatile("v_permlane32_swap_b32 %0, %1" : "+v"(a0), "+v"(b0));
      asm volatile("v_permlane32_swap_b32 %0, %1" : "+v"(a1), "+v"(b1));
      u32x4 tt;
      tt[0] = a0; tt[1] = a1; tt[2] = b0; tt[3] = b1;
      pa[ks] = __builtin_bit_cast(bf16x8, tt);
    }

    __builtin_amdgcn_s_setprio(1);
#pragma unroll
    for (int nte = 0; nte < 4; ++nte) {
      int rbase = (nte * 16 + (l31 >> 1)) * 128 + (lane & 1) * 64;
#pragma unroll
      for (int ks = 0; ks < 4; ++ks) {
        int colk = (ks * 16 + h * 8) ^ swV;
        bf16x8 vb = *(const bf16x8*)&Vc[rbase + colk];
        acc[nte] = mfma32(pa[ks], vb, acc[nte]);
      }
    }
    __builtin_amdgcn_s_setprio(0);
    __builtin_amdgcn_s_barrier();
  }

  float inv = 1.0f / lrun;
  int b_ = bh >> 3, h_ = bh & 7;
#pragma unroll
  for (int reg = 0; reg < 16; ++reg) {
    int qr = (reg & 3) + 8 * (reg >> 2) + 4 * h;
    float iq = __shfl(inv, qr);
    int q = qbase + qr;
    short* orow = Ctx + (((size_t)b_ * 2048 + q) * 8 + h_) * 128;
#pragma unroll
    for (int nte = 0; nte < 4; ++nte)
      orow[nte * 32 + l31] = bf16b(acc[nte][reg] * iq);
  }
}

// ---------- host ----------
extern "C" void kernel_launch(void* const* d_in, const int* in_sizes, int n_in,
                              void* d_out, int out_size, void* d_ws, size_t ws_size,
                              hipStream_t stream) {
  const float* q = (const float*)d_in[0];
  const float* k = (const float*)d_in[1];
  const float* v = (const float*)d_in[2];
  const float* Wq = (const float*)d_in[3];
  const float* bq = (const float*)d_in[4];
  const float* Wk = (const float*)d_in[5];
  const float* bk = (const float*)d_in[6];
  const float* Wv = (const float*)d_in[7];
  const float* bv = (const float*)d_in[8];
  const float* Wo = (const float*)d_in[9];
  const float* bo = (const float*)d_in[10];
  float* out = (float*)d_out;

  short* ws = (short*)d_ws;
  short* X3 = ws;                               // 3 * 8388608 shorts
  short* WT = X3 + (size_t)3 * 8388608;         // 4 * 1048576 shorts
  short* Qg = WT + (size_t)4 * 1048576;
  short* Kg = Qg + (size_t)8388608;
  short* Vtg = Kg + (size_t)8388608;
  short* Ctx = X3;  // X dead after projections; reuse for attention output

  hipLaunchKernelGGL(cvt_x, dim3(8192, 3), dim3(256), 0, stream, q, k, v, X3);
  hipLaunchKernelGGL(cvt_w, dim3(16, 16, 4), dim3(256), 0, stream, Wq, Wk, Wv, Wo, WT);
  hipLaunchKernelGGL(gemm256, dim3(384), dim3(512), 0, stream, X3, WT, bq, bk, bv,
                     bo, Qg, Kg, Vtg, out, 0, 384);
  hipLaunchKernelGGL(attn, dim3(16, 32), dim3(256), 0, stream, Qg, Kg, Vtg, Ctx);
  hipLaunchKernelGGL(gemm256, dim3(128), dim3(512), 0, stream, Ctx, WT, bq, bk, bv,
                     bo, Qg, Kg, Vtg, out, 3, 128);
}

// Round 5
// 228.596 us; speedup vs baseline: 1.0466x; 1.0466x over previous
//
#include <hip/hip_runtime.h>
#include <hip/hip_bf16.h>
#include <cstdint>

// ---------- types ----------
typedef __attribute__((ext_vector_type(4))) float f32x4;
typedef __attribute__((ext_vector_type(16))) float f32x16;
typedef __attribute__((ext_vector_type(8))) __bf16 bf16x8;
typedef __attribute__((ext_vector_type(4))) unsigned u32x4;

#define SCALE_Q 0.08838834764831845f  /* 1/sqrt(128) */

__device__ __forceinline__ short bf16b(float f) {
  unsigned u = __builtin_bit_cast(unsigned, f);
  unsigned r = (u + 0x7fffu + ((u >> 16) & 1u)) >> 16;
  return (short)r;
}

__device__ __forceinline__ unsigned packbf(float lo, float hi) {
  return (unsigned)(unsigned short)bf16b(lo) |
         ((unsigned)(unsigned short)bf16b(hi) << 16);
}

__device__ __forceinline__ f32x4 mfma16(bf16x8 a, bf16x8 b, f32x4 c) {
  return __builtin_amdgcn_mfma_f32_16x16x32_bf16(a, b, c, 0, 0, 0);
}
__device__ __forceinline__ f32x16 mfma32(bf16x8 a, bf16x8 b, f32x16 c) {
  return __builtin_amdgcn_mfma_f32_32x32x16_bf16(a, b, c, 0, 0, 0);
}

__device__ __forceinline__ void async16(void* lds, const void* g) {
  __builtin_amdgcn_global_load_lds(
      (const __attribute__((address_space(1))) unsigned int*)g,
      (__attribute__((address_space(3))) unsigned int*)lds, 16, 0, 0);
}

// ---------- kernel 1: fp32 -> bf16 for queries/keys/values ----------
__global__ void cvt_x(const float* __restrict__ q, const float* __restrict__ k,
                      const float* __restrict__ v, short* __restrict__ out) {
  const float* src = (blockIdx.y == 0) ? q : (blockIdx.y == 1 ? k : v);
  short* dst = out + (size_t)blockIdx.y * 8388608;
  size_t i = (size_t)blockIdx.x * 256 + threadIdx.x;
  float4 f = reinterpret_cast<const float4*>(src)[i];
  short4 o;
  o.x = bf16b(f.x); o.y = bf16b(f.y); o.z = bf16b(f.z); o.w = bf16b(f.w);
  reinterpret_cast<short4*>(dst)[i] = o;
}

// ---------- kernel 2: transpose + convert weights -> WT[z][N][K] bf16 ----------
__global__ void cvt_w(const float* __restrict__ Wq, const float* __restrict__ Wk,
                      const float* __restrict__ Wv, const float* __restrict__ Wo,
                      short* __restrict__ out) {
  int z = blockIdx.z;
  const float* W = (z == 0) ? Wq : (z == 1) ? Wk : (z == 2) ? Wv : Wo;
  float scale = (z == 0) ? SCALE_Q : 1.0f;
  __shared__ float t[64][65];
  int n0 = blockIdx.x * 64, k0 = blockIdx.y * 64;
  int c = threadIdx.x & 63, r0 = threadIdx.x >> 6;
#pragma unroll
  for (int rr = 0; rr < 16; ++rr) {
    int r = rr * 4 + r0;
    t[r][c] = W[(size_t)(k0 + r) * 1024 + n0 + c];
  }
  __syncthreads();
  short* dst = out + (size_t)z * 1048576;
#pragma unroll
  for (int rr = 0; rr < 16; ++rr) {
    int r = rr * 4 + r0;
    dst[(size_t)(n0 + r) * 1024 + k0 + c] = bf16b(t[c][r] * scale);
  }
}

// ---------- kernel 3: 256x256 8-phase GEMM (QKV proj z=0..2, out proj z=3) ----------
// Single-read fragments held in registers across the phases that consume them
// (m201's actual scheme: 24 ds_read_b128/wave/K-tile, not 48).
// ph1: load a0,b0 (12 reads) -> MFMA Q(0,0); ph2: load b1 (4) -> Q(0,1);
// ph3: load a1 (8) -> Q(1,0); ph4: no reads -> Q(1,1).
// Stage schedule (R4-proven race-free, unchanged): ph1->ABeta(t+1),
// ph2->BBeta(t+1) (other buffer); ph3->AAlpha(t+2), ph4->BAlpha(t+2)
// (current buffer); vmcnt(4) once per tile at ph4 (never 0 mid-loop).
#define LDA_FRAGS(dst, P, MH)                                                  \
  _Pragma("unroll") for (int mt = 0; mt < 4; ++mt)                             \
      _Pragma("unroll") for (int kk = 0; kk < 2; ++kk) {                       \
    int r = wr * 128 + MH * 64 + mt * 16 + l15;                                \
    dst[mt][kk] = *(const bf16x8*)((const char*)(P) + r * 128 +                \
                                   ((lg * 16 + kk * 64) ^ ((r & 7) << 4)));    \
  }
#define LDB_FRAGS(dst, P, NH)                                                  \
  _Pragma("unroll") for (int nt = 0; nt < 2; ++nt)                             \
      _Pragma("unroll") for (int kk = 0; kk < 2; ++kk) {                       \
    int r = wc * 64 + NH * 32 + nt * 16 + l15;                                 \
    dst[nt][kk] = *(const bf16x8*)((const char*)(P) + r * 128 +                \
                                   ((lg * 16 + kk * 64) ^ ((r & 7) << 4)));    \
  }
#define MFMA_Q(af, bfr, MH, NH)                                                \
  __builtin_amdgcn_s_setprio(1);                                               \
  _Pragma("unroll") for (int kk = 0; kk < 2; ++kk)                             \
      _Pragma("unroll") for (int mt = 0; mt < 4; ++mt)                         \
          _Pragma("unroll") for (int nt = 0; nt < 2; ++nt)                     \
              acc[MH * 4 + mt][NH * 2 + nt] = mfma16(                          \
                  af[mt][kk], bfr[nt][kk], acc[MH * 4 + mt][NH * 2 + nt]);     \
  __builtin_amdgcn_s_setprio(0);

__global__ __launch_bounds__(512, 2) void gemm256(
    const short* __restrict__ Ab, const short* __restrict__ WT,
    const float* __restrict__ bq, const float* __restrict__ bk,
    const float* __restrict__ bv, const float* __restrict__ bo,
    short* __restrict__ Qg, short* __restrict__ Kg, short* __restrict__ Vtg,
    float* __restrict__ Out, int zbase, int nwg) {
  __shared__ short LDS[65536];  // 128 KiB: A dbuf [2][256][64] + B dbuf
  short* LA = LDS;
  short* LB = LDS + 32768;

  int id = blockIdx.x;
  int cpx = nwg >> 3;
  int swz = (id & 7) * cpx + (id >> 3);  // XCD-contiguous chunks (nwg%8==0)
  int z = zbase + (swz >> 7);
  int rem = swz & 127;
  int m0 = (rem >> 2) * 256, n0 = (rem & 3) * 256;

  const short* Ag = (zbase == 0) ? Ab + (size_t)z * 8388608 : Ab;
  const short* Bg = WT + (size_t)z * 1048576;

  int tid = threadIdx.x;
  int lane = tid & 63, wave = tid >> 6;
  int wr = wave >> 2, wc = wave & 3, l15 = lane & 15, lg = lane >> 4;

  // ---- staging (linear LDS dest, inverse-swizzled global source) ----
  auto stageA = [&](short* buf, int k0, int h) {
#pragma unroll
    for (int ld = 0; ld < 2; ++ld) {
      int row = (2 * ld + h) * 64 + (tid >> 3);
      int gc = (tid & 7) ^ (row & 7);
      async16((char*)buf + row * 128 + (tid & 7) * 16,
              (const char*)Ag + (size_t)(m0 + row) * 2048 + k0 * 2 + gc * 16);
    }
  };
  auto stageB = [&](short* buf, int k0, int h) {
#pragma unroll
    for (int ld = 0; ld < 2; ++ld) {
      int idx = tid >> 3;
      int n = (h + 2 * (idx >> 5) + 4 * ld) * 32 + (idx & 31);
      int gc = (tid & 7) ^ (n & 7);
      async16((char*)buf + n * 128 + (tid & 7) * 16,
              (const char*)Bg + (size_t)(n0 + n) * 2048 + k0 * 2 + gc * 16);
    }
  };

  f32x4 acc[8][4];
#pragma unroll
  for (int i = 0; i < 8; ++i)
#pragma unroll
    for (int j = 0; j < 4; ++j) acc[i][j] = f32x4{0.f, 0.f, 0.f, 0.f};

  // ---- prologue: tile0 {Aa,Ba,Ab,Bb} + tile1 {Aa,Ba}; vmcnt(4) keeps
  // tile1's pair in flight, guarantees tile0 fully resident ----
  stageA(LA, 0, 0); stageB(LB, 0, 0); stageA(LA, 0, 1); stageB(LB, 0, 1);
  stageA(LA + 16384, 64, 0); stageB(LB + 16384, 64, 0);
  asm volatile("s_waitcnt vmcnt(4)" ::: "memory");
  __builtin_amdgcn_s_barrier();

  // ---- main loop: 16 K-tiles, 4 phases each, single-read frags ----
  for (int t = 0; t < 16; ++t) {
    short* Ap = LA + (t & 1) * 16384;
    short* Bp = LB + (t & 1) * 16384;
    short* Aq = LA + ((t & 1) ^ 1) * 16384;
    short* Bq = LB + ((t & 1) ^ 1) * 16384;
    bf16x8 a0[4][2], a1[4][2], b0[2][2], b1[2][2];
    // ph1: read a0,b0; stage ABeta(t+1) into other buffer
    LDA_FRAGS(a0, Ap, 0)
    LDB_FRAGS(b0, Bp, 0)
    if (t + 1 < 16) stageA(Aq, t * 64 + 64, 1);
    __builtin_amdgcn_s_barrier();
    MFMA_Q(a0, b0, 0, 0)
    __builtin_amdgcn_s_barrier();
    // ph2: read b1; stage BBeta(t+1) into other buffer
    LDB_FRAGS(b1, Bp, 1)
    if (t + 1 < 16) stageB(Bq, t * 64 + 64, 1);
    __builtin_amdgcn_s_barrier();
    MFMA_Q(a0, b1, 0, 1)
    __builtin_amdgcn_s_barrier();
    // ph3: read a1; stage AAlpha(t+2) into current buffer (A0 last read ph1)
    LDA_FRAGS(a1, Ap, 1)
    if (t + 2 < 16) stageA(Ap, t * 64 + 128, 0);
    __builtin_amdgcn_s_barrier();
    MFMA_Q(a1, b0, 1, 0)
    __builtin_amdgcn_s_barrier();
    // ph4: no reads; stage BAlpha(t+2) (B0 last read ph1); counted vmcnt
    if (t + 2 < 16) stageB(Bp, t * 64 + 128, 0);
    if (t <= 13) asm volatile("s_waitcnt vmcnt(4)" ::: "memory");
    else if (t == 14) asm volatile("s_waitcnt vmcnt(0)" ::: "memory");
    __builtin_amdgcn_s_barrier();
    MFMA_Q(a1, b1, 1, 1)
    __builtin_amdgcn_s_barrier();
  }

  // ---- epilogue ----
  if (z == 2) {
    // Vt via LDS transpose: LDS[col n 256][m 128] per wr-half, coalesced stores
    unsigned* L32 = (unsigned*)LDS;
#pragma unroll
    for (int pass = 0; pass < 2; ++pass) {
      if (wr == pass) {
#pragma unroll
        for (int nt4 = 0; nt4 < 4; ++nt4) {
          int ncol = wc * 64 + nt4 * 16 + l15;
          float bb = bv[n0 + ncol];
#pragma unroll
          for (int mt8 = 0; mt8 < 8; ++mt8) {
            unsigned lo = packbf(acc[mt8][nt4][0] + bb, acc[mt8][nt4][1] + bb);
            unsigned hi = packbf(acc[mt8][nt4][2] + bb, acc[mt8][nt4][3] + bb);
            int base = ncol * 68 + mt8 * 8 + lg * 2;
            L32[base] = lo;
            L32[base + 1] = hi;
          }
        }
      }
      asm volatile("s_waitcnt lgkmcnt(0)" ::: "memory");
      __builtin_amdgcn_s_barrier();
#pragma unroll
      for (int i = 0; i < 8; ++i) {
        int idx = i * 512 + tid;
        int col = idx >> 4, ch = idx & 15;
        u32x4 val = *(u32x4*)&L32[col * 68 + ch * 4];
        int nf = n0 + col, e_ = nf & 127, h_ = nf >> 7;
        size_t bh = (size_t)(m0 >> 11) * 8 + h_;
        int sb = ((m0 & 2047) + pass * 128 + ch * 8) ^ (((e_ >> 1) & 7) << 3);
        *(u32x4*)&Vtg[(bh * 128 + e_) * 2048 + sb] = val;
      }
      asm volatile("s_waitcnt lgkmcnt(0)" ::: "memory");
      __builtin_amdgcn_s_barrier();
    }
  } else {
    const float* bias = (z == 0) ? bq : (z == 1) ? bk : bo;
    float bsc = (z == 0) ? SCALE_Q : 1.0f;
#pragma unroll
    for (int nt4 = 0; nt4 < 4; ++nt4) {
      int n = n0 + wc * 64 + nt4 * 16 + l15;
      float bb = bias[n] * bsc;
#pragma unroll
      for (int mt8 = 0; mt8 < 8; ++mt8)
#pragma unroll
        for (int j = 0; j < 4; ++j) {
          int m = m0 + wr * 128 + mt8 * 16 + lg * 4 + j;
          float c = acc[mt8][nt4][j] + bb;
          if (z == 3) {
            Out[(size_t)m * 1024 + n] = c;
          } else {
            int s_ = m & 2047, b_ = m >> 11, h_ = n >> 7, e_ = n & 127;
            size_t bh = (size_t)b_ * 8 + h_;
            if (z == 0) Qg[(bh * 2048 + s_) * 128 + e_] = bf16b(c);
            else Kg[(bh * 2048 + s_) * 128 + (e_ ^ ((s_ & 15) << 3))] = bf16b(c);
          }
        }
    }
  }
}

// ---------- kernel 4: flash attention, 32x32 swapped-QK^T, in-register P ----------
__global__ __launch_bounds__(256, 2) void attn(const short* __restrict__ Qg,
                                               const short* __restrict__ Kg,
                                               const short* __restrict__ Vtg,
                                               short* __restrict__ Ctx) {
  __shared__ short Ks[2][8192];  // [64 s][128 e], e ^ ((s&15)<<3)
  __shared__ short Vs[2][8192];  // [64 r][(e&1)*64 + (s ^ ((r&7)<<3))], r=e>>1
  int tid = threadIdx.x;
  int lane = tid & 63, wave = tid >> 6;
  int l31 = lane & 31, h = lane >> 5;
  int bh = blockIdx.y, qb = blockIdx.x;
  int qbase = qb * 128 + wave * 32;
  const short* Qp = Qg + (size_t)bh * 2048 * 128;
  const char* Kbase = (const char*)(Kg + (size_t)bh * 2048 * 128);
  const char* Vbase = (const char*)(Vtg + (size_t)bh * 128 * 2048);

  auto stage = [&](int t, int buf) {
    int s0 = t * 64;
    char* kd = (char*)&Ks[buf][0];
    char* vd = (char*)&Vs[buf][0];
#pragma unroll
    for (int i = 0; i < 4; ++i)
      async16(kd + i * 4096 + tid * 16,
              Kbase + (size_t)s0 * 256 + i * 4096 + tid * 16);
#pragma unroll
    for (int i = 0; i < 4; ++i) {
      int e = i * 32 + 2 * (tid >> 4) + ((tid >> 3) & 1);
      async16(vd + i * 4096 + tid * 16,
              Vbase + (size_t)e * 4096 + s0 * 2 + (tid & 7) * 16);
    }
  };

  stage(0, 0);

  bf16x8 qa[8];
  const short* qrow = Qp + (size_t)(qbase + l31) * 128 + h * 8;
#pragma unroll
  for (int ksl = 0; ksl < 8; ++ksl) qa[ksl] = *(const bf16x8*)(qrow + ksl * 16);

  f32x16 acc[4];
#pragma unroll
  for (int i = 0; i < 4; ++i)
#pragma unroll
    for (int r = 0; r < 16; ++r) acc[i][r] = 0.f;
  float mrun = -1e30f, lrun = 0.f;

  int swK = (l31 & 15) << 3;
  int swV = ((l31 >> 1) & 7) << 3;

  for (int t = 0; t < 32; ++t) {
    int cur = t & 1;
    if (t < 31) {
      stage(t + 1, cur ^ 1);
      asm volatile("s_waitcnt vmcnt(8)" ::: "memory");
    } else {
      asm volatile("s_waitcnt vmcnt(0)" ::: "memory");
    }
    __builtin_amdgcn_s_barrier();

    const short* Kc = Ks[cur];
    const short* Vc = Vs[cur];

    f32x16 st0, st1;
#pragma unroll
    for (int r = 0; r < 16; ++r) { st0[r] = 0.f; st1[r] = 0.f; }
    __builtin_amdgcn_s_setprio(1);
#pragma unroll
    for (int ksl = 0; ksl < 8; ++ksl) {
      int col = (ksl * 16 + h * 8) ^ swK;
      bf16x8 ka0 = *(const bf16x8*)&Kc[l31 * 128 + col];
      bf16x8 ka1 = *(const bf16x8*)&Kc[(32 + l31) * 128 + col];
      st0 = mfma32(ka0, qa[ksl], st0);
      st1 = mfma32(ka1, qa[ksl], st1);
    }
    __builtin_amdgcn_s_setprio(0);

    float mx = st0[0];
#pragma unroll
    for (int r = 1; r < 16; ++r) mx = fmaxf(mx, st0[r]);
#pragma unroll
    for (int r = 0; r < 16; ++r) mx = fmaxf(mx, st1[r]);
    mx = fmaxf(mx, __shfl_xor(mx, 32));
    int skip = __all(mx - mrun <= 5.0f);
    float mn = mrun, sf = 1.f;
    if (!skip) {
      mn = fmaxf(mrun, mx);
      sf = __expf(mrun - mn);
      mrun = mn;
    }
    float rs = 0.f;
#pragma unroll
    for (int r = 0; r < 16; ++r) { float p = __expf(st0[r] - mn); st0[r] = p; rs += p; }
#pragma unroll
    for (int r = 0; r < 16; ++r) { float p = __expf(st1[r] - mn); st1[r] = p; rs += p; }
    rs += __shfl_xor(rs, 32);
    if (!skip) {
      lrun = lrun * sf + rs;
#pragma unroll
      for (int reg = 0; reg < 16; ++reg) {
        float s4 = __shfl(sf, (reg & 3) + 8 * (reg >> 2) + 4 * h);
#pragma unroll
        for (int nte = 0; nte < 4; ++nte) acc[nte][reg] *= s4;
      }
    } else {
      lrun += rs;
    }

    unsigned w0[8], w1[8];
#pragma unroll
    for (int m = 0; m < 8; ++m) {
      w0[m] = packbf(st0[2 * m], st0[2 * m + 1]);
      w1[m] = packbf(st1[2 * m], st1[2 * m + 1]);
    }
    bf16x8 pa[4];
#pragma unroll
    for (int ks = 0; ks < 4; ++ks) {
      const unsigned* w = (ks & 2) ? w1 : w0;
      int mb = (ks & 1) * 4;
      unsigned a0 = w[mb], b0 = w[mb + 2];
      unsigned a1 = w[mb + 1], b1 = w[mb + 3];
      asm volatile("v_permlane32_swap_b32 %0, %1" : "+v"(a0), "+v"(b0));
      asm volatile("v_permlane32_swap_b32 %0, %1" : "+v"(a1), "+v"(b1));
      u32x4 tt;
      tt[0] = a0; tt[1] = a1; tt[2] = b0; tt[3] = b1;
      pa[ks] = __builtin_bit_cast(bf16x8, tt);
    }

    __builtin_amdgcn_s_setprio(1);
#pragma unroll
    for (int nte = 0; nte < 4; ++nte) {
      int rbase = (nte * 16 + (l31 >> 1)) * 128 + (lane & 1) * 64;
#pragma unroll
      for (int ks = 0; ks < 4; ++ks) {
        int colk = (ks * 16 + h * 8) ^ swV;
        bf16x8 vb = *(const bf16x8*)&Vc[rbase + colk];
        acc[nte] = mfma32(pa[ks], vb, acc[nte]);
      }
    }
    __builtin_amdgcn_s_setprio(0);
    __builtin_amdgcn_s_barrier();
  }

  float inv = 1.0f / lrun;
  int b_ = bh >> 3, h_ = bh & 7;
#pragma unroll
  for (int reg = 0; reg < 16; ++reg) {
    int qr = (reg & 3) + 8 * (reg >> 2) + 4 * h;
    float iq = __shfl(inv, qr);
    int q = qbase + qr;
    short* orow = Ctx + (((size_t)b_ * 2048 + q) * 8 + h_) * 128;
#pragma unroll
    for (int nte = 0; nte < 4; ++nte)
      orow[nte * 32 + l31] = bf16b(acc[nte][reg] * iq);
  }
}

// ---------- host ----------
extern "C" void kernel_launch(void* const* d_in, const int* in_sizes, int n_in,
                              void* d_out, int out_size, void* d_ws, size_t ws_size,
                              hipStream_t stream) {
  const float* q = (const float*)d_in[0];
  const float* k = (const float*)d_in[1];
  const float* v = (const float*)d_in[2];
  const float* Wq = (const float*)d_in[3];
  const float* bq = (const float*)d_in[4];
  const float* Wk = (const float*)d_in[5];
  const float* bk = (const float*)d_in[6];
  const float* Wv = (const float*)d_in[7];
  const float* bv = (const float*)d_in[8];
  const float* Wo = (const float*)d_in[9];
  const float* bo = (const float*)d_in[10];
  float* out = (float*)d_out;

  short* ws = (short*)d_ws;
  short* X3 = ws;                               // 3 * 8388608 shorts
  short* WT = X3 + (size_t)3 * 8388608;         // 4 * 1048576 shorts
  short* Qg = WT + (size_t)4 * 1048576;
  short* Kg = Qg + (size_t)8388608;
  short* Vtg = Kg + (size_t)8388608;
  short* Ctx = X3;  // X dead after projections; reuse for attention output

  hipLaunchKernelGGL(cvt_x, dim3(8192, 3), dim3(256), 0, stream, q, k, v, X3);
  hipLaunchKernelGGL(cvt_w, dim3(16, 16, 4), dim3(256), 0, stream, Wq, Wk, Wv, Wo, WT);
  hipLaunchKernelGGL(gemm256, dim3(384), dim3(512), 0, stream, X3, WT, bq, bk, bv,
                     bo, Qg, Kg, Vtg, out, 0, 384);
  hipLaunchKernelGGL(attn, dim3(16, 32), dim3(256), 0, stream, Qg, Kg, Vtg, Ctx);
  hipLaunchKernelGGL(gemm256, dim3(128), dim3(512), 0, stream, Ctx, WT, bq, bk, bv,
                     bo, Qg, Kg, Vtg, out, 3, 128);
}

// Round 6
// 209.562 us; speedup vs baseline: 1.1417x; 1.0908x over previous
//
#include <hip/hip_runtime.h>
#include <hip/hip_bf16.h>
#include <cstdint>

// ---------- types ----------
typedef __attribute__((ext_vector_type(4))) float f32x4;
typedef __attribute__((ext_vector_type(16))) float f32x16;
typedef __attribute__((ext_vector_type(8))) __bf16 bf16x8;
typedef __attribute__((ext_vector_type(4))) unsigned u32x4;

#define SCALE_Q 0.08838834764831845f  /* 1/sqrt(128) */

__device__ __forceinline__ short bf16b(float f) {
  unsigned u = __builtin_bit_cast(unsigned, f);
  unsigned r = (u + 0x7fffu + ((u >> 16) & 1u)) >> 16;
  return (short)r;
}

__device__ __forceinline__ unsigned packbf(float lo, float hi) {
  return (unsigned)(unsigned short)bf16b(lo) |
         ((unsigned)(unsigned short)bf16b(hi) << 16);
}

__device__ __forceinline__ f32x4 mfma16(bf16x8 a, bf16x8 b, f32x4 c) {
  return __builtin_amdgcn_mfma_f32_16x16x32_bf16(a, b, c, 0, 0, 0);
}
__device__ __forceinline__ f32x16 mfma32(bf16x8 a, bf16x8 b, f32x16 c) {
  return __builtin_amdgcn_mfma_f32_32x32x16_bf16(a, b, c, 0, 0, 0);
}

__device__ __forceinline__ void async16(void* lds, const void* g) {
  __builtin_amdgcn_global_load_lds(
      (const __attribute__((address_space(1))) unsigned int*)g,
      (__attribute__((address_space(3))) unsigned int*)lds, 16, 0, 0);
}

// ---------- kernel 1: fp32 -> bf16 for queries/keys/values ----------
__global__ void cvt_x(const float* __restrict__ q, const float* __restrict__ k,
                      const float* __restrict__ v, short* __restrict__ out) {
  const float* src = (blockIdx.y == 0) ? q : (blockIdx.y == 1 ? k : v);
  short* dst = out + (size_t)blockIdx.y * 8388608;
  size_t i = (size_t)blockIdx.x * 256 + threadIdx.x;
  float4 f = reinterpret_cast<const float4*>(src)[i];
  short4 o;
  o.x = bf16b(f.x); o.y = bf16b(f.y); o.z = bf16b(f.z); o.w = bf16b(f.w);
  reinterpret_cast<short4*>(dst)[i] = o;
}

// ---------- kernel 2: transpose + convert weights -> WT[z][N][K] bf16 ----------
__global__ void cvt_w(const float* __restrict__ Wq, const float* __restrict__ Wk,
                      const float* __restrict__ Wv, const float* __restrict__ Wo,
                      short* __restrict__ out) {
  int z = blockIdx.z;
  const float* W = (z == 0) ? Wq : (z == 1) ? Wk : (z == 2) ? Wv : Wo;
  float scale = (z == 0) ? SCALE_Q : 1.0f;
  __shared__ float t[64][65];
  int n0 = blockIdx.x * 64, k0 = blockIdx.y * 64;
  int c = threadIdx.x & 63, r0 = threadIdx.x >> 6;
#pragma unroll
  for (int rr = 0; rr < 16; ++rr) {
    int r = rr * 4 + r0;
    t[r][c] = W[(size_t)(k0 + r) * 1024 + n0 + c];
  }
  __syncthreads();
  short* dst = out + (size_t)z * 1048576;
#pragma unroll
  for (int rr = 0; rr < 16; ++rr) {
    int r = rr * 4 + r0;
    dst[(size_t)(n0 + r) * 1024 + k0 + c] = bf16b(t[c][r] * scale);
  }
}

// ---------- kernel 3: 128x128 2-phase GEMM (R2-proven structure) ----------
// z=0..2: QKV projections; z=3: output projection (fp32 epilogue).
// Fixes over R2: (1) T1 XCD chunk-swizzle on 1D grid, n-fastest so each XCD
// streams contiguous A-panels through its private L2; (2) T2 both-sides LDS
// swizzle (stage source chunk ^ (row&7), read byte ^ ((row&7)<<4)) — the
// R4/R5-proven correct pair; (3) out-proj folded in (no half-empty dispatch).
__global__ __launch_bounds__(256, 2) void gemm128(
    const short* __restrict__ Ab, const short* __restrict__ WT,
    const float* __restrict__ bq, const float* __restrict__ bk,
    const float* __restrict__ bv, const float* __restrict__ bo,
    short* __restrict__ Qg, short* __restrict__ Kg, short* __restrict__ Vtg,
    float* __restrict__ Out, int zbase, int nwg) {
  __shared__ short As[8192], Bs[8192];

  int cpx = nwg >> 3;
  int swz = ((int)blockIdx.x & 7) * cpx + ((int)blockIdx.x >> 3);
  int z, rem;
  if (zbase == 0) { z = swz >> 9; rem = swz & 511; }   // 512 tiles per z (64m x 8n)
  else { z = 3; rem = swz; }
  int m0 = (rem >> 3) * 128, n0 = (rem & 7) * 128;     // n fastest: A-panel reuse

  const short* A = (zbase == 0) ? Ab + (size_t)z * 8388608 : Ab;
  const short* Bn = WT + (size_t)z * 1048576;

  int tid = threadIdx.x;
  int lane = tid & 63, wave = tid >> 6;
  int wr = wave >> 1, wc = wave & 1, l15 = lane & 15, lg = lane >> 4;

  f32x4 acc[4][4];
#pragma unroll
  for (int mt = 0; mt < 4; ++mt)
#pragma unroll
    for (int nt = 0; nt < 4; ++nt) acc[mt][nt] = f32x4{0.f, 0.f, 0.f, 0.f};

  for (int k0 = 0; k0 < 1024; k0 += 64) {
#pragma unroll
    for (int i = 0; i < 4; ++i) {
      int r = (tid >> 3) + i * 32, c = tid & 7;
      int gc = c ^ (r & 7);  // inverse-swizzled source, linear LDS dest
      async16((char*)As + i * 4096 + tid * 16,
              (const char*)A + ((size_t)(m0 + r) * 1024 + k0) * 2 + gc * 16);
      async16((char*)Bs + i * 4096 + tid * 16,
              (const char*)Bn + ((size_t)(n0 + r) * 1024 + k0) * 2 + gc * 16);
    }
    __syncthreads();
#pragma unroll
    for (int kk = 0; kk < 2; ++kk) {
      bf16x8 a[4], b[4];
#pragma unroll
      for (int mt = 0; mt < 4; ++mt) {
        int r = wr * 64 + mt * 16 + l15;
        a[mt] = *(const bf16x8*)((const char*)As + r * 128 +
                                 ((lg * 16 + kk * 64) ^ ((r & 7) << 4)));
      }
#pragma unroll
      for (int nt = 0; nt < 4; ++nt) {
        int r = wc * 64 + nt * 16 + l15;
        b[nt] = *(const bf16x8*)((const char*)Bs + r * 128 +
                                 ((lg * 16 + kk * 64) ^ ((r & 7) << 4)));
      }
#pragma unroll
      for (int mt = 0; mt < 4; ++mt)
#pragma unroll
        for (int nt = 0; nt < 4; ++nt)
          acc[mt][nt] = mfma16(a[mt], b[nt], acc[mt][nt]);
    }
    __syncthreads();
  }

  // ---- epilogue (R2-proven layouts; z=3 fp32 direct) ----
#pragma unroll
  for (int mt = 0; mt < 4; ++mt)
#pragma unroll
    for (int nt = 0; nt < 4; ++nt) {
      int n = n0 + wc * 64 + nt * 16 + l15;
      float bb = (z == 0)   ? bq[n] * SCALE_Q
                 : (z == 1) ? bk[n]
                 : (z == 2) ? bv[n]
                            : bo[n];
#pragma unroll
      for (int j = 0; j < 4; ++j) {
        int m = m0 + wr * 64 + mt * 16 + lg * 4 + j;
        float cv = acc[mt][nt][j] + bb;
        if (z == 3) {
          Out[(size_t)m * 1024 + n] = cv;
        } else {
          short o = bf16b(cv);
          int s_ = m & 2047, b_ = m >> 11, h_ = n >> 7, e_ = n & 127;
          size_t bh = (size_t)b_ * 8 + h_;
          if (z == 0)
            Qg[(bh * 2048 + s_) * 128 + e_] = o;
          else if (z == 1)
            Kg[(bh * 2048 + s_) * 128 + (e_ ^ ((s_ & 15) << 3))] = o;
          else
            Vtg[(bh * 128 + e_) * 2048 + (s_ ^ (((e_ >> 1) & 7) << 3))] = o;
        }
      }
    }
}

// ---------- kernel 4: flash attention, 32x32 swapped-QK^T, in-register P ----------
__global__ __launch_bounds__(256, 2) void attn(const short* __restrict__ Qg,
                                               const short* __restrict__ Kg,
                                               const short* __restrict__ Vtg,
                                               short* __restrict__ Ctx) {
  __shared__ short Ks[2][8192];  // [64 s][128 e], e ^ ((s&15)<<3)
  __shared__ short Vs[2][8192];  // [64 r][(e&1)*64 + (s ^ ((r&7)<<3))], r=e>>1
  int tid = threadIdx.x;
  int lane = tid & 63, wave = tid >> 6;
  int l31 = lane & 31, h = lane >> 5;
  int bh = blockIdx.y, qb = blockIdx.x;
  int qbase = qb * 128 + wave * 32;
  const short* Qp = Qg + (size_t)bh * 2048 * 128;
  const char* Kbase = (const char*)(Kg + (size_t)bh * 2048 * 128);
  const char* Vbase = (const char*)(Vtg + (size_t)bh * 128 * 2048);

  auto stage = [&](int t, int buf) {
    int s0 = t * 64;
    char* kd = (char*)&Ks[buf][0];
    char* vd = (char*)&Vs[buf][0];
#pragma unroll
    for (int i = 0; i < 4; ++i)
      async16(kd + i * 4096 + tid * 16,
              Kbase + (size_t)s0 * 256 + i * 4096 + tid * 16);
#pragma unroll
    for (int i = 0; i < 4; ++i) {
      int e = i * 32 + 2 * (tid >> 4) + ((tid >> 3) & 1);
      async16(vd + i * 4096 + tid * 16,
              Vbase + (size_t)e * 4096 + s0 * 2 + (tid & 7) * 16);
    }
  };

  stage(0, 0);

  bf16x8 qa[8];
  const short* qrow = Qp + (size_t)(qbase + l31) * 128 + h * 8;
#pragma unroll
  for (int ksl = 0; ksl < 8; ++ksl) qa[ksl] = *(const bf16x8*)(qrow + ksl * 16);

  f32x16 acc[4];
#pragma unroll
  for (int i = 0; i < 4; ++i)
#pragma unroll
    for (int r = 0; r < 16; ++r) acc[i][r] = 0.f;
  float mrun = -1e30f, lrun = 0.f;

  int swK = (l31 & 15) << 3;
  int swV = ((l31 >> 1) & 7) << 3;

  for (int t = 0; t < 32; ++t) {
    int cur = t & 1;
    if (t < 31) {
      stage(t + 1, cur ^ 1);
      asm volatile("s_waitcnt vmcnt(8)" ::: "memory");
    } else {
      asm volatile("s_waitcnt vmcnt(0)" ::: "memory");
    }
    __builtin_amdgcn_s_barrier();

    const short* Kc = Ks[cur];
    const short* Vc = Vs[cur];

    f32x16 st0, st1;
#pragma unroll
    for (int r = 0; r < 16; ++r) { st0[r] = 0.f; st1[r] = 0.f; }
    __builtin_amdgcn_s_setprio(1);
#pragma unroll
    for (int ksl = 0; ksl < 8; ++ksl) {
      int col = (ksl * 16 + h * 8) ^ swK;
      bf16x8 ka0 = *(const bf16x8*)&Kc[l31 * 128 + col];
      bf16x8 ka1 = *(const bf16x8*)&Kc[(32 + l31) * 128 + col];
      st0 = mfma32(ka0, qa[ksl], st0);
      st1 = mfma32(ka1, qa[ksl], st1);
    }
    __builtin_amdgcn_s_setprio(0);

    float mx = st0[0];
#pragma unroll
    for (int r = 1; r < 16; ++r) mx = fmaxf(mx, st0[r]);
#pragma unroll
    for (int r = 0; r < 16; ++r) mx = fmaxf(mx, st1[r]);
    mx = fmaxf(mx, __shfl_xor(mx, 32));
    int skip = __all(mx - mrun <= 5.0f);
    float mn = mrun, sf = 1.f;
    if (!skip) {
      mn = fmaxf(mrun, mx);
      sf = __expf(mrun - mn);
      mrun = mn;
    }
    float rs = 0.f;
#pragma unroll
    for (int r = 0; r < 16; ++r) { float p = __expf(st0[r] - mn); st0[r] = p; rs += p; }
#pragma unroll
    for (int r = 0; r < 16; ++r) { float p = __expf(st1[r] - mn); st1[r] = p; rs += p; }
    rs += __shfl_xor(rs, 32);
    if (!skip) {
      lrun = lrun * sf + rs;
#pragma unroll
      for (int reg = 0; reg < 16; ++reg) {
        float s4 = __shfl(sf, (reg & 3) + 8 * (reg >> 2) + 4 * h);
#pragma unroll
        for (int nte = 0; nte < 4; ++nte) acc[nte][reg] *= s4;
      }
    } else {
      lrun += rs;
    }

    unsigned w0[8], w1[8];
#pragma unroll
    for (int m = 0; m < 8; ++m) {
      w0[m] = packbf(st0[2 * m], st0[2 * m + 1]);
      w1[m] = packbf(st1[2 * m], st1[2 * m + 1]);
    }
    bf16x8 pa[4];
#pragma unroll
    for (int ks = 0; ks < 4; ++ks) {
      const unsigned* w = (ks & 2) ? w1 : w0;
      int mb = (ks & 1) * 4;
      unsigned a0 = w[mb], b0 = w[mb + 2];
      unsigned a1 = w[mb + 1], b1 = w[mb + 3];
      asm volatile("v_permlane32_swap_b32 %0, %1" : "+v"(a0), "+v"(b0));
      asm volatile("v_permlane32_swap_b32 %0, %1" : "+v"(a1), "+v"(b1));
      u32x4 tt;
      tt[0] = a0; tt[1] = a1; tt[2] = b0; tt[3] = b1;
      pa[ks] = __builtin_bit_cast(bf16x8, tt);
    }

    __builtin_amdgcn_s_setprio(1);
#pragma unroll
    for (int nte = 0; nte < 4; ++nte) {
      int rbase = (nte * 16 + (l31 >> 1)) * 128 + (lane & 1) * 64;
#pragma unroll
      for (int ks = 0; ks < 4; ++ks) {
        int colk = (ks * 16 + h * 8) ^ swV;
        bf16x8 vb = *(const bf16x8*)&Vc[rbase + colk];
        acc[nte] = mfma32(pa[ks], vb, acc[nte]);
      }
    }
    __builtin_amdgcn_s_setprio(0);
    __builtin_amdgcn_s_barrier();
  }

  float inv = 1.0f / lrun;
  int b_ = bh >> 3, h_ = bh & 7;
#pragma unroll
  for (int reg = 0; reg < 16; ++reg) {
    int qr = (reg & 3) + 8 * (reg >> 2) + 4 * h;
    float iq = __shfl(inv, qr);
    int q = qbase + qr;
    short* orow = Ctx + (((size_t)b_ * 2048 + q) * 8 + h_) * 128;
#pragma unroll
    for (int nte = 0; nte < 4; ++nte)
      orow[nte * 32 + l31] = bf16b(acc[nte][reg] * iq);
  }
}

// ---------- host ----------
extern "C" void kernel_launch(void* const* d_in, const int* in_sizes, int n_in,
                              void* d_out, int out_size, void* d_ws, size_t ws_size,
                              hipStream_t stream) {
  const float* q = (const float*)d_in[0];
  const float* k = (const float*)d_in[1];
  const float* v = (const float*)d_in[2];
  const float* Wq = (const float*)d_in[3];
  const float* bq = (const float*)d_in[4];
  const float* Wk = (const float*)d_in[5];
  const float* bk = (const float*)d_in[6];
  const float* Wv = (const float*)d_in[7];
  const float* bv = (const float*)d_in[8];
  const float* Wo = (const float*)d_in[9];
  const float* bo = (const float*)d_in[10];
  float* out = (float*)d_out;

  short* ws = (short*)d_ws;
  short* X3 = ws;                               // 3 * 8388608 shorts
  short* WT = X3 + (size_t)3 * 8388608;         // 4 * 1048576 shorts
  short* Qg = WT + (size_t)4 * 1048576;
  short* Kg = Qg + (size_t)8388608;
  short* Vtg = Kg + (size_t)8388608;
  short* Ctx = X3;  // X dead after projections; reuse for attention output

  hipLaunchKernelGGL(cvt_x, dim3(8192, 3), dim3(256), 0, stream, q, k, v, X3);
  hipLaunchKernelGGL(cvt_w, dim3(16, 16, 4), dim3(256), 0, stream, Wq, Wk, Wv, Wo, WT);
  hipLaunchKernelGGL(gemm128, dim3(1536), dim3(256), 0, stream, X3, WT, bq, bk, bv,
                     bo, Qg, Kg, Vtg, out, 0, 1536);
  hipLaunchKernelGGL(attn, dim3(16, 32), dim3(256), 0, stream, Qg, Kg, Vtg, Ctx);
  hipLaunchKernelGGL(gemm128, dim3(512), dim3(256), 0, stream, Ctx, WT, bq, bk, bv,
                     bo, Qg, Kg, Vtg, out, 3, 512);
}